// Round 3
// baseline (293.984 us; speedup 1.0000x reference)
//
#include <hip/hip_runtime.h>

// Problem constants
constexpr int Bc  = 4;
constexpr int Sc  = 384;
constexpr int Dc  = 300;
constexpr int Ec  = 50;
constexpr int HDc = 150;          // D / L
constexpr int WHC = 2*HDc + Ec;   // 350, Wh row length

// ---------------------------------------------------------------------------
// prep: column sums of Wh_e, Wh_1, Wh_2 and sum(bh) into small buffer sm
// layout (floats): [0..49] we_colsum, [64..213] w1_colsum, [224..373] w2_colsum,
//                  [384] sum(bh)
// ---------------------------------------------------------------------------
__global__ void prep_kernel(const float* __restrict__ Wh,
                            const float* __restrict__ bh,
                            float* __restrict__ sm) {
    int t = threadIdx.x;  // 512 threads
    if (t < Ec) {
        float s = 0.f;
        for (int e = 0; e < Ec; ++e) s += Wh[e*WHC + t];
        sm[t] = s;
    } else if (t >= 64 && t < 64 + HDc) {
        int h = t - 64;
        float s = 0.f;
        for (int e = 0; e < Ec; ++e) s += Wh[e*WHC + Ec + h];
        sm[t] = s;
    } else if (t >= 224 && t < 224 + HDc) {
        int h = t - 224;
        float s = 0.f;
        for (int e = 0; e < Ec; ++e) s += Wh[e*WHC + Ec + HDc + h];
        sm[t] = s;
    } else if (t == 384) {
        float s = 0.f;
        for (int e = 0; e < Ec; ++e) s += bh[e];
        sm[t] = s;
    }
}

// ---------------------------------------------------------------------------
// reduce_adj2: one coalesced pass over adj (B,S,S,E) via LDS staging.
//   A0[row] = (sum_e adj)/E ; wadj[row] = sum_e adj*we_colsum[e]
// ---------------------------------------------------------------------------
__global__ __launch_bounds__(256)
void reduce_adj2(const float* __restrict__ adj, const float* __restrict__ sm,
                 float* __restrict__ A0, float* __restrict__ wadj) {
    __shared__ float wec[64];
    __shared__ float tile[256 * 51];
    int t = threadIdx.x;
    if (t < Ec) wec[t] = sm[t];
    long base = (long)blockIdx.x * (256 * 50);
    const float4* p4 = (const float4*)(adj + base);
    for (int i = t; i < 3200; i += 256) {
        float4 v = p4[i];
        int e = 4 * i;
        const float* vp = (const float*)&v;
        #pragma unroll
        for (int j = 0; j < 4; ++j) {
            int ee = e + j;
            tile[(ee / 50) * 51 + (ee % 50)] = vp[j];
        }
    }
    __syncthreads();
    const float* row = tile + t * 51;
    float s = 0.f, w = 0.f;
    #pragma unroll
    for (int i = 0; i < 50; ++i) { float v = row[i]; s += v; w += v * wec[i]; }
    int r = blockIdx.x * 256 + t;
    A0[r]   = s * (1.0f / Ec);
    wadj[r] = w;
}

// ---------------------------------------------------------------------------
// Templated fp32 GEMM, 256 threads, BK=32, register-prefetch double buffer.
//   C[b] = op(A[b]) @ op(B) [+ D[b]] [+ bscale*bias] [relu]
// WCAT: B is the virtual concat [W0 | W1[:, :300] | Wout] (transposed access)
// A1M : A element = (wadj + s1[k] + s2[m] + sum_bh) / E   (fused A1)
// ---------------------------------------------------------------------------
template<int BM, int BN, int TMq, int TNq, int WCAT, int A1M>
__global__ __launch_bounds__(256)
void gemmT(const float* __restrict__ A, const float* __restrict__ B0,
           const float* __restrict__ B1, const float* __restrict__ B2,
           const float* __restrict__ Dm, const float* __restrict__ bias,
           const float* __restrict__ s12, const float* __restrict__ smp,
           float* __restrict__ C,
           int M, int N, int K, int lda, int ldb, int ldd, int ldc,
           long sA, long sB, long sD, long sC,
           int transB, float bscale, int relu) {
    constexpr int BK = 32;
    constexpr int LA = BM + 4;   // rows 16B-aligned -> ds_read_b128/b64 clean
    constexpr int LB = BN + 4;
    constexpr int nA = BM * BK / 256;
    constexpr int nB = BN * BK / 256;

    int b = blockIdx.z;
    A += (long)b * sA;
    const float* Bp = B0 + (long)b * sB;
    const float* Dp = Dm ? Dm + (long)b * sD : nullptr;
    C += (long)b * sC;
    const float* s12b = A1M ? s12 + (long)2 * Sc * b : nullptr;
    float sbh = A1M ? smp[384] : 0.f;

    __shared__ float As[BK * LA];
    __shared__ float Bs[BK * LB];

    int tid = threadIdx.x;
    int tx = tid & 15, ty = tid >> 4;
    int m0 = blockIdx.y * BM, n0 = blockIdx.x * BN;

    float rA[nA], rB[nB];

    auto loadA = [&](int k0) {
        #pragma unroll
        for (int j = 0; j < nA; ++j) {
            int i = tid + j * 256;
            int kl = i % BK, ml = i / BK;
            int m = m0 + ml, k = k0 + kl;
            float v = 0.f;
            if (m < M && k < K) {
                v = A[(long)m * lda + k];
                if (A1M) v = (v + s12b[2 * k] + s12b[2 * m + 1] + sbh) * (1.0f / Ec);
            }
            rA[j] = v;
        }
    };
    auto loadB = [&](int k0) {
        if (WCAT) {
            #pragma unroll
            for (int j = 0; j < nB; ++j) {
                int i = tid + j * 256;
                int kl = i % BK, nl = i / BK;
                int k = k0 + kl, n = n0 + nl;
                float v = 0.f;
                if (k < K && n < N) {
                    const float* bp; int ld, nn;
                    if (n < HDc)          { bp = B0; ld = Dc;        nn = n; }
                    else if (n < 2 * HDc) { bp = B1; ld = Dc + HDc;  nn = n - HDc; }
                    else                  { bp = B2; ld = Dc;        nn = n - 2 * HDc; }
                    v = bp[(long)nn * ld + k];
                }
                rB[j] = v;
            }
        } else if (transB) {
            #pragma unroll
            for (int j = 0; j < nB; ++j) {
                int i = tid + j * 256;
                int kl = i % BK, nl = i / BK;
                int k = k0 + kl, n = n0 + nl;
                rB[j] = (k < K && n < N) ? Bp[(long)n * ldb + k] : 0.f;
            }
        } else {
            #pragma unroll
            for (int j = 0; j < nB; ++j) {
                int i = tid + j * 256;
                int nl = i % BN, kl = i / BN;
                int k = k0 + kl, n = n0 + nl;
                rB[j] = (k < K && n < N) ? Bp[(long)k * ldb + n] : 0.f;
            }
        }
    };
    auto stash = [&]() {
        #pragma unroll
        for (int j = 0; j < nA; ++j) {
            int i = tid + j * 256;
            int kl = i % BK, ml = i / BK;
            As[kl * LA + ml] = rA[j];
        }
        if (WCAT || transB) {
            #pragma unroll
            for (int j = 0; j < nB; ++j) {
                int i = tid + j * 256;
                int kl = i % BK, nl = i / BK;
                Bs[kl * LB + nl] = rB[j];
            }
        } else {
            #pragma unroll
            for (int j = 0; j < nB; ++j) {
                int i = tid + j * 256;
                int nl = i % BN, kl = i / BN;
                Bs[kl * LB + nl] = rB[j];
            }
        }
    };

    float acc[TMq][TNq] = {};

    loadA(0); loadB(0);
    for (int k0 = 0; k0 < K; k0 += BK) {
        __syncthreads();
        stash();
        __syncthreads();
        if (k0 + BK < K) { loadA(k0 + BK); loadB(k0 + BK); }
        #pragma unroll
        for (int kk = 0; kk < BK; ++kk) {
            float a_[TMq], b_[TNq];
            #pragma unroll
            for (int i = 0; i < TMq; ++i) a_[i] = As[kk * LA + ty * TMq + i];
            #pragma unroll
            for (int j = 0; j < TNq; ++j) b_[j] = Bs[kk * LB + tx * TNq + j];
            #pragma unroll
            for (int i = 0; i < TMq; ++i)
                #pragma unroll
                for (int j = 0; j < TNq; ++j)
                    acc[i][j] += a_[i] * b_[j];
        }
    }

    #pragma unroll
    for (int i = 0; i < TMq; ++i) {
        int m = m0 + ty * TMq + i;
        if (m >= M) continue;
        #pragma unroll
        for (int j = 0; j < TNq; ++j) {
            int n = n0 + tx * TNq + j;
            if (n >= N) continue;
            float v = acc[i][j];
            if (Dp)   v += Dp[(long)m * ldd + n];
            if (bias) v += bscale * bias[n];
            if (relu) v = fmaxf(v, 0.f);
            C[(long)m * ldc + n] = v;
        }
    }
}

// ---------------------------------------------------------------------------
// s1s2: wave-per-row dot products of G0 (stride 300, cols 0..149) with
// w1/w2 column sums. s12[2r]=s1, s12[2r+1]=s2.
// ---------------------------------------------------------------------------
__global__ __launch_bounds__(256)
void s1s2_w(const float* __restrict__ G, const float* __restrict__ sm,
            float* __restrict__ s12) {
    int wave = (blockIdx.x * 256 + threadIdx.x) >> 6;
    int lane = threadIdx.x & 63;
    if (wave < Bc * Sc) {
        const float* g = G + (long)wave * Dc;   // cols 0..149 hold G0
        float a = 0.f, c = 0.f;
        #pragma unroll
        for (int h0 = 0; h0 < HDc; h0 += 64) {
            int h = h0 + lane;
            if (h < HDc) {
                float v = g[h];
                a += v * sm[64 + h];
                c += v * sm[224 + h];
            }
        }
        #pragma unroll
        for (int off = 32; off; off >>= 1) {
            a += __shfl_down(a, off);
            c += __shfl_down(c, off);
        }
        if (lane == 0) { s12[2 * wave] = a; s12[2 * wave + 1] = c; }
    }
}

extern "C" void kernel_launch(void* const* d_in, const int* in_sizes, int n_in,
                              void* d_out, int out_size, void* d_ws, size_t ws_size,
                              hipStream_t stream) {
    const float* adj  = (const float*)d_in[0];
    const float* X    = (const float*)d_in[1];
    const float* W0   = (const float*)d_in[2];
    const float* b0   = (const float*)d_in[3];
    const float* W1   = (const float*)d_in[4];
    const float* b1   = (const float*)d_in[5];
    const float* Wh   = (const float*)d_in[6];
    const float* bh   = (const float*)d_in[7];
    const float* Wout = (const float*)d_in[8];
    const float* bout = (const float*)d_in[9];
    float* out = (float*)d_out;

    // workspace layout (floats)
    float* ws   = (float*)d_ws;
    float* sm   = ws;                         // 512
    float* A0   = sm + 512;                   // B*S*S
    float* wadj = A0 + Bc * Sc * Sc;          // B*S*S
    float* R    = wadj + Bc * Sc * Sc;        // 1536 x 600: [P0 | Q1->P1 | R2]
    float* Gbuf = R + (long)Bc * Sc * 600;    // 1536 x 300: [G0 | G1]
    float* s12  = Gbuf + (long)Bc * Sc * Dc;  // B*S*2

    const int nrows = Bc * Sc * Sc;           // 589824 = 2304*256
    const long MS = (long)Sc * Sc;            // per-batch adj stride

    // 1) weight column sums + sum(bh)
    prep_kernel<<<1, 512, 0, stream>>>(Wh, bh, sm);

    // 2) one HBM pass over adj: A0 (scaled) + weighted edge reduction
    reduce_adj2<<<nrows / 256, 256, 0, stream>>>(adj, sm, A0, wadj);

    // 3) R = X @ [W0 | W1a | Wout]^T   (M=1536, N=600, K=300) -> P0|Q1|R2
    gemmT<64,64,4,4,1,0><<<dim3(10, 24, 1), 256, 0, stream>>>(
        X, W0, W1, Wout, nullptr, nullptr, nullptr, nullptr, R,
        Bc*Sc, 600, Dc, Dc, 0, 0, 600,
        0, 0, 0, 0, 1, 0.f, 0);

    // 4) G0 = relu(A0 @ P0 + P0 + 2*b0)   (batched; P0 = R[:, 0:150])
    gemmT<32,32,2,2,0,0><<<dim3(5, 12, Bc), 256, 0, stream>>>(
        A0, R, nullptr, nullptr, R, b0, nullptr, nullptr, Gbuf,
        Sc, HDc, Sc, Sc, 600, 600, Dc,
        MS, (long)Sc * 600, (long)Sc * 600, (long)Sc * Dc,
        0, 2.0f, 1);

    // 5) s1/s2 row reductions of G0 (wave per row)
    s1s2_w<<<(Bc * Sc) / 4, 256, 0, stream>>>(Gbuf, sm, s12);

    // 6) P1 = Q1 + G0 @ W1b^T   (in-place into R[:, 150:300]; K=150)
    gemmT<32,32,2,2,0,0><<<dim3(5, 48, 1), 256, 0, stream>>>(
        Gbuf, W1 + Dc, nullptr, nullptr, R + HDc, nullptr, nullptr, nullptr, R + HDc,
        Bc*Sc, HDc, HDc, Dc, Dc + HDc, 600, 600,
        0, 0, 0, 0, 1, 0.f, 0);

    // 7) G1 = relu(A1 @ P1 + P1 + 2*b1), A1 built on the fly from wadj+s12
    gemmT<32,32,2,2,0,1><<<dim3(5, 12, Bc), 256, 0, stream>>>(
        wadj, R + HDc, nullptr, nullptr, R + HDc, b1, s12, sm, Gbuf + HDc,
        Sc, HDc, Sc, Sc, 600, 600, Dc,
        MS, (long)Sc * 600, (long)Sc * 600, (long)Sc * Dc,
        0, 2.0f, 1);

    // 8) out = [G0|G1] @ Wout^T + R2 + bout   (M=1536, N=300, K=300)
    gemmT<32,64,2,4,0,0><<<dim3(5, 48, 1), 256, 0, stream>>>(
        Gbuf, Wout, nullptr, nullptr, R + 2 * HDc, bout, nullptr, nullptr, out,
        Bc*Sc, Dc, Dc, Dc, Dc, 600, Dc,
        0, 0, 0, 0, 1, 1.0f, 0);
}